// Round 13
// baseline (688.992 us; speedup 1.0000x reference)
//
#include <hip/hip_runtime.h>
#include <math.h>

#define BB 8
#define NN 2048
#define KNNK 8
#define SEG 16
#define SEGN (NN/SEG)
#define OBJ 224
#define HWD (OBJ*OBJ)
#define NQ (BB*NN)

// MFMA vector types (gfx950 v_mfma_f32_16x16x32_f16: A/B = 8 x f16, C/D = 4 x f32)
typedef _Float16 f16x8 __attribute__((ext_vector_type(8)));
typedef _Float16 f16x4 __attribute__((ext_vector_type(4)));
typedef float    f32x4v __attribute__((ext_vector_type(4)));

// ---------------- workspace layout (float units) ----------------
constexpr size_t RES_SZ  = (size_t)BB*HWD*64;     // 25,690,112 floats
constexpr size_t F_SZ    = (size_t)BB*NN*64;
constexpr size_t F0_SZ   = (size_t)BB*NN*8;
constexpr size_t RES_OFF = 0;
constexpr size_t H1_OFF  = RES_SZ;                // also aliases KNN partials (pre-conv)
constexpr size_t F_OFF   = 2*RES_SZ;
constexpr size_t F0_OFF  = F_OFF + F_SZ;
constexpr size_t BP_OFF  = F0_OFF + F0_SZ;
constexpr size_t GS_OFF  = BP_OFF + 128;
constexpr size_t GM_OFF  = GS_OFF + 64;
constexpr size_t WT1_OFF = GM_OFF + 64;           // 92160 f16 = 46080 floats (frag weights)
constexpr size_t WTF_SZ  = 46080;
constexpr size_t WT2_OFF = WT1_OFF + WTF_SZ;
constexpr size_t INT_OFF = WT2_OFF + WTF_SZ;

// ---------------- K0: conv weights -> split-f16 MFMA B-frags (fused pair) -
// Layout: wf[(((tap*2 + kb)*2 + hl)*64 + o)*40 + kk], kk = k within 32-block,
// kk-stride padded 32->40 f16. hl=0: hi = (f16)w, hl=1: lo = w - hi.
// R13: both weight tensors in ONE launch (block-range split).
__global__ void k0_wtf(const float* __restrict__ w1, const float* __restrict__ w2,
                       _Float16* __restrict__ wf1, _Float16* __restrict__ wf2) {
    int i = blockIdx.x*256 + threadIdx.x;
    const float* w = w1; _Float16* wf = wf1;
    if (i >= 92160) { i -= 92160; w = w2; wf = wf2; }
    if (i >= 92160) return;
    int kk = i % 40;
    int o  = (i/40) & 63;
    int hl = (i/2560) & 1;
    int kb = (i/5120) & 1;
    int tp = i/10240;
    _Float16 v = (_Float16)0.f;
    if (kk < 32) {
        int c = kb*32 + kk;
        float val = w[(size_t)(o*64 + c)*9 + tp];
        _Float16 hi = (_Float16)val;
        v = hl ? (_Float16)(val - (float)hi) : hi;
    }
    wf[i] = v;
}

// ---------------- K1: per-batch grid params — FROZEN (arcp f32, R11) -----
__global__ void k1_params(const float* __restrict__ pc, float* __restrict__ bparam) {
    __shared__ float r0[256], r1[256], r2[256], r3[256];
    __shared__ float sh[4];
    int b = blockIdx.x, t = threadIdx.x;
    const float* p = pc + (size_t)b*NN*3;
    float mnx=1e30f, mxx=-1e30f, mny=1e30f, mxy=-1e30f;
    for (int n=t; n<NN; n+=256) {
        float x=p[3*n], y=p[3*n+1];
        mnx=fminf(mnx,x); mxx=fmaxf(mxx,x); mny=fminf(mny,y); mxy=fmaxf(mxy,y);
    }
    r0[t]=mnx; r1[t]=mxx; r2[t]=mny; r3[t]=mxy;
    __syncthreads();
    for (int s=128; s>0; s>>=1) {
        if (t<s) { r0[t]=fminf(r0[t],r0[t+s]); r1[t]=fmaxf(r1[t],r1[t+s]);
                   r2[t]=fminf(r2[t],r2[t+s]); r3[t]=fmaxf(r3[t],r3[t+s]); }
        __syncthreads();
    }
    if (t==0) {
        float rx = __fsub_rn(r1[0], r0[0]);
        float ry = __fsub_rn(r3[0], r2[0]);
        sh[0]=r0[0]; sh[1]=r2[0];
        float c221 = __fdiv_rn(1.0f, (float)(OBJ-3));
        float grid = __fmul_rn(fmaxf(rx,ry), c221);
        sh[2] = grid;
        sh[3] = __fdiv_rn(1.0f, grid);               // hoisted reciprocal (arcp)
    }
    __syncthreads();
    float minx=sh[0], miny=sh[1], rgrid=sh[3];
    mnx=1e30f; mxx=-1e30f; mny=1e30f; mxy=-1e30f;
    for (int n=t; n<NN; n+=256) {
        float ix = floorf(__fmul_rn(__fsub_rn(p[3*n],   minx), rgrid));
        float iy = floorf(__fmul_rn(__fsub_rn(p[3*n+1], miny), rgrid));
        mnx=fminf(mnx,ix); mxx=fmaxf(mxx,ix); mny=fminf(mny,iy); mxy=fmaxf(mxy,iy);
    }
    __syncthreads();
    r0[t]=mnx; r1[t]=mxx; r2[t]=mny; r3[t]=mxy;
    __syncthreads();
    for (int s=128; s>0; s>>=1) {
        if (t<s) { r0[t]=fminf(r0[t],r0[t+s]); r1[t]=fmaxf(r1[t],r1[t+s]);
                   r2[t]=fminf(r2[t],r2[t+s]); r3[t]=fmaxf(r3[t],r3[t+s]); }
        __syncthreads();
    }
    if (t==0) {
        float cx = floorf((r1[0] + 2.0f + r0[0]) * 0.5f);
        float cy = floorf((r3[0] + 2.0f + r2[0]) * 0.5f);
        bparam[b*8+0]=minx; bparam[b*8+1]=miny; bparam[b*8+2]=sh[3];
        bparam[b*8+3]=112.0f - cx - 1.0f;
        bparam[b*8+4]=112.0f - cy - 1.0f;
    }
}

// ---------------- K2+K3 fused (block-uniform branch) — bodies FROZEN -----
__global__ void k23_fused(const float* __restrict__ pc, const float* __restrict__ bparam,
                          int* __restrict__ lin, const float* __restrict__ w_in,
                          const float* __restrict__ b_in, float* __restrict__ f0) {
    if (blockIdx.x < 64) {
        // ---- k2: linear grid indices (arcp) ----
        int i = blockIdx.x*256 + threadIdx.x;
        int b = i / NN;
        float x = pc[(size_t)i*3], y = pc[(size_t)i*3+1];
        float minx=bparam[b*8], miny=bparam[b*8+1], rgrid=bparam[b*8+2];
        float offx=bparam[b*8+3], offy=bparam[b*8+4];
        float ix = floorf(__fmul_rn(__fsub_rn(x, minx), rgrid));
        float iy = floorf(__fmul_rn(__fsub_rn(y, miny), rgrid));
        const float o9x[9] = {-1,-1,-1, 0,0,0, 1,1,1};
        const float o9y[9] = {-1, 0, 1,-1,0,1,-1,0,1};
#pragma unroll
        for (int j=0; j<9; ++j) {
            float dx = ix + o9x[j] + 1.0f + offx;
            float dy = iy + o9y[j] + 1.0f + offy;
            dx += (dx < 0.f ? 1.f : 0.f) - (dx > 223.f ? 1.f : 0.f);
            dy += (dy < 0.f ? 1.f : 0.f) - (dy > 223.f ? 1.f : 0.f);
            lin[(size_t)i*9 + j] = (int)(dx*224.f + dy);
        }
    } else {
        // ---- k3: f0 = pc @ w_in^T + b_in ----
        int i = (blockIdx.x - 64)*256 + threadIdx.x;
        int o = i & 7; int bn = i >> 3;
        float x=pc[(size_t)bn*3], y=pc[(size_t)bn*3+1], z=pc[(size_t)bn*3+2];
        f0[i] = x*w_in[o*3] + y*w_in[o*3+1] + z*w_in[o*3+2] + b_in[o];
    }
}

// ---------------- K4: segmented KNN (SEG=16, transposed out; split launch)
// VALU-throughput-bound (92% busy) — algorithmic floor for exact scan.
// R13: launched as TWO half-dispatches (segoff 0/8) purely for rocprof
// top-5 granularity; identical total work.
__global__ __launch_bounds__(256) void k4_knn(const float* __restrict__ pc,
                                              float* __restrict__ pd,
                                              int* __restrict__ pi, int segoff) {
    __shared__ float4 pts[SEGN];
    int b = blockIdx.y, t = threadIdx.x, seg = blockIdx.z + segoff;
    const float* p = pc + (size_t)b*NN*3;
    int m0 = seg*SEGN;
    for (int m=t; m<SEGN; m+=256) {
        int mm = m0 + m;
        float x=p[3*mm], y=p[3*mm+1], z=p[3*mm+2];
        float sq = __fadd_rn(__fadd_rn(__fmul_rn(x,x), __fmul_rn(y,y)), __fmul_rn(z,z));
        pts[m] = make_float4(x, y, z, sq);
    }
    __syncthreads();
    int n = blockIdx.x*256 + t;
    float mx = p[3*n], my = p[3*n+1], mz = p[3*n+2];
    float msq = __fadd_rn(__fadd_rn(__fmul_rn(mx,mx), __fmul_rn(my,my)), __fmul_rn(mz,mz));
    float bd[KNNK]; int bi[KNNK];
#pragma unroll
    for (int j=0; j<KNNK; ++j) { bd[j]=1e30f; bi[j]=0; }
#pragma unroll 8
    for (int m=0; m<SEGN; ++m) {
        float4 q = pts[m];
        float dot = __fadd_rn(__fadd_rn(__fmul_rn(mz,q.z), __fmul_rn(my,q.y)),
                              __fmul_rn(mx,q.x));
        float d = __fsub_rn(__fadd_rn(msq, q.w), __fmul_rn(2.0f, dot));
        if (d < bd[KNNK-1]) {
            float v=d; int vi=m0+m;
#pragma unroll
            for (int j=0; j<KNNK; ++j) {
                if (v < bd[j]) { float tv=bd[j]; int ti=bi[j]; bd[j]=v; bi[j]=vi; v=tv; vi=ti; }
            }
        }
    }
    size_t qidx = (size_t)b*NN + n;
#pragma unroll
    for (int j=0; j<KNNK; ++j) {
        pd[(size_t)(seg*KNNK + j)*NQ + qidx] = bd[j];
        pi[(size_t)(seg*KNNK + j)*NQ + qidx] = bi[j];
    }
}

// ---------------- K4b: merge SEG sorted top-8 lists (static insertion) ---
// Coalesced transposed loads; 256 blocks x 64 thr = every CU active.
// Traversal (s-major, j-minor, strict-less insert) — FROZEN semantics.
__global__ __launch_bounds__(64) void k4b_merge(const float* __restrict__ pd,
                                                const int* __restrict__ pi,
                                                int* __restrict__ nidx) {
    int q = blockIdx.x*64 + threadIdx.x;
    if (q >= NQ) return;
    float bd[KNNK]; int bi[KNNK];
#pragma unroll
    for (int j=0; j<KNNK; ++j) { bd[j]=1e30f; bi[j]=0x7fffffff; }
#pragma unroll
    for (int s=0; s<SEG; ++s) {
#pragma unroll
        for (int j=0; j<KNNK; ++j) {
            float v = pd[(size_t)(s*KNNK + j)*NQ + q];
            int  vi = pi[(size_t)(s*KNNK + j)*NQ + q];
            if (v < bd[KNNK-1]) {
                float cv=v; int ci=vi;
#pragma unroll
                for (int qq=0; qq<KNNK; ++qq) {
                    if (cv < bd[qq]) { float tv=bd[qq]; int ti=bi[qq]; bd[qq]=cv; bi[qq]=ci; cv=tv; ci=ti; }
                }
            }
        }
    }
#pragma unroll
    for (int j=0; j<KNNK; ++j) nidx[(size_t)q*KNNK + j] = bi[j];
}

// ---------------- feat builder (shared by K5/K6) ----------------
__device__ __forceinline__ void build_feat(int t, int b, int n0,
        const float* __restrict__ f0, const int* __restrict__ nidx,
        float feat[4][8][16]) {
    int pt = t >> 6, k = (t >> 3) & 7, c = t & 7;
    int n  = n0 + pt;
    int nb = nidx[((size_t)b*NN + n)*8 + k];
    float f0c = f0[((size_t)b*NN + n)*8 + c];
    float fnc = f0[((size_t)b*NN + nb)*8 + c];
    feat[pt][k][c]   = fnc - f0c;
    feat[pt][k][c+8] = f0c;
}

// ---------------- K5: GroupNorm stats pass ----------------
__global__ __launch_bounds__(256) void k5_stats(const float* __restrict__ f0,
        const int* __restrict__ nidx, const float* __restrict__ w_graph,
        float* __restrict__ gsum) {
    __shared__ float wgT[16*64];
    __shared__ float feat[4][8][16];
    __shared__ float part[4][4][2];
    int t = threadIdx.x;
    for (int i=t; i<1024; i+=256) wgT[(i&15)*64 + (i>>4)] = w_graph[i];
    int blk = blockIdx.x;
    int b = blk >> 9, n0 = (blk & 511)*4;
    build_feat(t, b, n0, f0, nidx, feat);
    __syncthreads();
    int pt = t >> 6, o = t & 63;
    float s = 0.f, s2 = 0.f;
#pragma unroll
    for (int k=0; k<8; ++k) {
        float g = 0.f;
#pragma unroll
        for (int c=0; c<16; ++c) g = fmaf(feat[pt][k][c], wgT[c*64+o], g);
        s += g; s2 += g*g;
    }
#pragma unroll
    for (int off=8; off; off>>=1) {
        s  += __shfl_down(s,  off, 16);
        s2 += __shfl_down(s2, off, 16);
    }
    if ((o & 15) == 0) { part[pt][o>>4][0] = s; part[pt][o>>4][1] = s2; }
    __syncthreads();
    if (t < 8) {
        int grp = t >> 1, which = t & 1;
        float v = part[0][grp][which] + part[1][grp][which]
                + part[2][grp][which] + part[3][grp][which];
        atomicAdd(&gsum[(b*4+grp)*2 + which], v);
    }
}

__global__ void k5b_finalize(const float* __restrict__ gsum, float* __restrict__ gmu) {
    int t = threadIdx.x;
    if (t < 32) {
        const float cnt = (float)(NN*KNNK*16);
        float mu = gsum[t*2] / cnt;
        float var = gsum[t*2+1] / cnt - mu*mu;
        gmu[t*2]   = mu;
        gmu[t*2+1] = 1.0f / sqrtf(var + 1e-5f);
    }
}

// ---------------- K6: normalize + leaky + max_k + proj ----------------
__global__ __launch_bounds__(256) void k6_point(const float* __restrict__ f0,
        const int* __restrict__ nidx, const float* __restrict__ w_graph,
        const float* __restrict__ gmu, const float* __restrict__ gn_g,
        const float* __restrict__ gn_b, const float* __restrict__ w_proj,
        const float* __restrict__ b_proj, float* __restrict__ f) {
    __shared__ float wgT[16*64];
    __shared__ float wpT[64*64];
    __shared__ float feat[4][8][16];
    __shared__ float gmax_s[4][64];
    int t = threadIdx.x;
    for (int i=t; i<1024; i+=256) wgT[(i&15)*64 + (i>>4)] = w_graph[i];
    for (int i=t; i<4096; i+=256) wpT[(i&63)*64 + (i>>6)] = w_proj[i];
    int blk = blockIdx.x;
    int b = blk >> 9, n0 = (blk & 511)*4;
    build_feat(t, b, n0, f0, nidx, feat);
    __syncthreads();
    int pt = t >> 6, o = t & 63;
    int grp = o >> 4;
    float mu = gmu[(b*4+grp)*2], rsig = gmu[(b*4+grp)*2+1];
    float ga = gn_g[o], be = gn_b[o];
    float gm = -1e30f;
#pragma unroll
    for (int k=0; k<8; ++k) {
        float g = 0.f;
#pragma unroll
        for (int c=0; c<16; ++c) g = fmaf(feat[pt][k][c], wgT[c*64+o], g);
        float v = (g - mu)*rsig*ga + be;
        v = (v >= 0.f) ? v : 0.2f*v;
        gm = fmaxf(gm, v);
    }
    gmax_s[pt][o] = gm;
    __syncthreads();
    float acc = b_proj[o];
#pragma unroll
    for (int c=0; c<64; ++c) acc = fmaf(gmax_s[pt][c], wpT[c*64+o], acc);
    f[((size_t)b*NN + n0 + pt)*64 + o] = acc;
}

// ---------------- K7: scatter-sum onto NHWC grid (all batches) -----------
__global__ __launch_bounds__(256) void k7_scatter(const float* __restrict__ f,
        const int* __restrict__ lin, float* __restrict__ res) {
    int blk = blockIdx.x, t = threadIdx.x;
    int b = blk >> 9;
    int n = (blk & 511)*4 + (t >> 6);
    int o = t & 63;
    size_t bn = (size_t)b*NN + n;
    float v = f[bn*64 + o];
#pragma unroll
    for (int j=0; j<9; ++j) {
        int cell = lin[bn*9 + j];
        if (cell >= 0 && cell < HWD)
            atomicAdd(&res[((size_t)b*HWD + cell)*64 + o], v);
    }
}

// ======================= split-f16 MFMA conv engine (R10 config, frozen) ==
// R10: row-major K-loop (ds_read 288->120/wave) + all-36-frag weights in
// registers at (256,1). FROZEN.
#define LDS4_BYTES 51840   // haloH [180][72]f16 + haloL

#define MFMA16(A,B,C) __builtin_amdgcn_mfma_f32_16x16x32_f16(A,B,C,0,0,0)

// one halo row R: load 12 A-frags, apply all valid (dy,dx) taps.
// m = R - dy must be in [0,7]; bounds are compile-time for literal R.
#define ROWC(R) { \
    f16x8 ah0[3], al0[3], ah1[3], al1[3]; \
    _Pragma("unroll") \
    for (int dx = 0; dx < 3; ++dx) { \
        int off_ = ((R)*18 + lr + dx)*72 + lg*8; \
        ah0[dx] = *(const f16x8*)&haloH[off_]; \
        al0[dx] = *(const f16x8*)&haloL[off_]; \
        ah1[dx] = *(const f16x8*)&haloH[off_ + 32]; \
        al1[dx] = *(const f16x8*)&haloL[off_ + 32]; \
    } \
    _Pragma("unroll") \
    for (int dy = 0; dy < 3; ++dy) { \
        if ((R) - dy >= 0 && (R) - dy <= 7) { \
            _Pragma("unroll") \
            for (int dx = 0; dx < 3; ++dx) { \
                acc[(R)-dy] = MFMA16(ah0[dx], wh0[dy*3+dx], acc[(R)-dy]); \
                acc[(R)-dy] = MFMA16(al0[dx], wh0[dy*3+dx], acc[(R)-dy]); \
                acc[(R)-dy] = MFMA16(ah0[dx], wl0[dy*3+dx], acc[(R)-dy]); \
                acc[(R)-dy] = MFMA16(ah1[dx], wh1[dy*3+dx], acc[(R)-dy]); \
                acc[(R)-dy] = MFMA16(al1[dx], wh1[dy*3+dx], acc[(R)-dy]); \
                acc[(R)-dy] = MFMA16(ah1[dx], wl1[dy*3+dx], acc[(R)-dy]); \
            } \
        } \
    } }

__device__ __forceinline__ void conv_mfma_body(
        const float* __restrict__ sp, const _Float16* __restrict__ wf,
        _Float16* haloH, _Float16* haloL,
        int x0, int y0, int t, int wid, int lr, int lg, f32x4v acc[8]) {
    // ---- halo stage: 10x18 cells x 64ch fp32 -> hi/lo f16 (batched) ----
    float4 vreg[12];
#pragma unroll
    for (int j = 0; j < 12; ++j) {
        int i = j*256 + t; if (i > 2879) i = 2879;     // dup-load, harmless
        int cell = i >> 4, c4 = i & 15;
        int gy = y0 - 1 + cell/18, gx = x0 - 1 + cell%18;
        int cy = gy < 0 ? 0 : (gy > OBJ-1 ? OBJ-1 : gy);
        int cx = gx < 0 ? 0 : (gx > OBJ-1 ? OBJ-1 : gx);
        vreg[j] = *(const float4*)(sp + ((size_t)cy*OBJ + cx)*64 + c4*4);
    }
#pragma unroll
    for (int j = 0; j < 12; ++j) {
        int i = j*256 + t;
        if (i <= 2879) {
            int cell = i >> 4, c4 = i & 15;
            int gy = y0 - 1 + cell/18, gx = x0 - 1 + cell%18;
            bool inb = ((unsigned)gy < (unsigned)OBJ) && ((unsigned)gx < (unsigned)OBJ);
            float4 v = vreg[j];
            if (!inb) v = make_float4(0.f,0.f,0.f,0.f);
            _Float16 a0=(_Float16)v.x, a1=(_Float16)v.y, a2=(_Float16)v.z, a3=(_Float16)v.w;
            f16x4 hv = {a0, a1, a2, a3};
            f16x4 lv = {(_Float16)(v.x-(float)a0), (_Float16)(v.y-(float)a1),
                        (_Float16)(v.z-(float)a2), (_Float16)(v.w-(float)a3)};
            *(f16x4*)&haloH[cell*72 + c4*4] = hv;
            *(f16x4*)&haloL[cell*72 + c4*4] = lv;
        }
    }
    // ---- all 36 weight B-frags into registers (144 VGPR, L2-hot) ----
    // wf addr = tap*10240 + kb*5120 + hl*2560 + o*40 + kk
    const int obase = (16*wid + lr)*40 + lg*8;
    f16x8 wh0[9], wl0[9], wh1[9], wl1[9];
#pragma unroll
    for (int tp = 0; tp < 9; ++tp) {
        const _Float16* wb_ = wf + (size_t)(tp*10240) + obase;
        wh0[tp] = *(const f16x8*)wb_;
        wl0[tp] = *(const f16x8*)(wb_ + 2560);
        wh1[tp] = *(const f16x8*)(wb_ + 5120);
        wl1[tp] = *(const f16x8*)(wb_ + 7680);
    }
    __syncthreads();
    // ---- barrier-free row-major K-loop: 10 halo rows ----
    ROWC(0) ROWC(1) ROWC(2) ROWC(3) ROWC(4)
    ROWC(5) ROWC(6) ROWC(7) ROWC(8) ROWC(9)
}

// ---------------- K8: conv3x3 + scale/shift + relu (MFMA, 16x8 tile) -----
__global__ __launch_bounds__(256, 1) void k8m_conv1(
        const float* __restrict__ src, const _Float16* __restrict__ wf,
        const float* __restrict__ g1, const float* __restrict__ b1,
        float* __restrict__ dst) {
    __shared__ __align__(16) char smem[LDS4_BYTES];
    _Float16* haloH = (_Float16*)smem;
    _Float16* haloL = (_Float16*)(smem + 25920);
    // XCD swizzle: batch = flat&7, tile = flat>>3 (bijective, 3136%8==0)
    int flat = blockIdx.x + 14*(blockIdx.y + 28*blockIdx.z);
    int b = flat & 7, rem = flat >> 3;
    int by = rem/14, bx = rem - by*14;
    int x0 = bx*16, y0 = by*8;
    int t = threadIdx.x, wid = t >> 6, lr = t & 15, lg = (t >> 4) & 3;
    f32x4v acc[8];
#pragma unroll
    for (int m=0;m<8;++m) acc[m] = (f32x4v){0.f,0.f,0.f,0.f};
    conv_mfma_body(src + (size_t)b*HWD*64, wf, haloH, haloL,
                   x0, y0, t, wid, lr, lg, acc);
    // ---- epilogue: scale/shift + relu, store NHWC ----
    float gv = g1[16*wid+lr], bv = b1[16*wid+lr];
    float* dp = dst + (size_t)b*HWD*64;
#pragma unroll
    for (int m = 0; m < 8; ++m) {
        size_t rowb = ((size_t)(y0+m)*OBJ + x0)*64 + 16*wid + lr;
#pragma unroll
        for (int r = 0; r < 4; ++r) {
            int px = lg*4 + r;
            dp[rowb + (size_t)px*64] = fmaxf(fmaf(acc[m][r], gv, bv), 0.f);
        }
    }
}

// ---------------- K9: conv3x3 + bn + residual-relu + blkout + img head ---
__global__ __launch_bounds__(256, 1) void k9m_conv2(
        const float* __restrict__ h1, const _Float16* __restrict__ wf,
        const float* __restrict__ g2, const float* __restrict__ b2,
        const float* __restrict__ resi,
        const float* __restrict__ wbk, const float* __restrict__ bbk,
        const float* __restrict__ wim, const float* __restrict__ bim,
        float* __restrict__ outp) {
    __shared__ __align__(16) char smem[LDS4_BYTES];
    _Float16* haloH = (_Float16*)smem;
    _Float16* haloL = (_Float16*)(smem + 25920);
    int flat = blockIdx.x + 14*(blockIdx.y + 28*blockIdx.z);
    int b = flat & 7, rem = flat >> 3;
    int by = rem/14, bx = rem - by*14;
    int x0 = bx*16, y0 = by*8;
    int t = threadIdx.x, wid = t >> 6, lr = t & 15, lg = (t >> 4) & 3;
    f32x4v acc[8];
#pragma unroll
    for (int m=0;m<8;++m) acc[m] = (f32x4v){0.f,0.f,0.f,0.f};
    conv_mfma_body(h1 + (size_t)b*HWD*64, wf, haloH, haloL,
                   x0, y0, t, wid, lr, lg, acc);
    // ---- wbk B-frags: global f32 -> hi/lo f16 regs (named, no staging) ----
    f16x8 wbh0, wbl0, wbh1, wbl1;
#define LOADWBK(KB, H, L) { \
    const float* wp_ = wbk + (size_t)(16*wid+lr)*64 + (KB)*32 + lg*8; \
    float4 w0_ = *(const float4*)wp_; \
    float4 w1_ = *(const float4*)(wp_+4); \
    const float* we_ = (const float*)&w0_; \
    const float* wo_ = (const float*)&w1_; \
    _Float16 h_[8]; _Float16 l_[8]; \
    _Pragma("unroll") \
    for (int e=0;e<4;++e) { h_[e]=(_Float16)we_[e]; l_[e]=(_Float16)(we_[e]-(float)h_[e]); } \
    _Pragma("unroll") \
    for (int e=0;e<4;++e) { h_[4+e]=(_Float16)wo_[e]; l_[4+e]=(_Float16)(wo_[e]-(float)h_[4+e]); } \
    H = (f16x8){h_[0],h_[1],h_[2],h_[3],h_[4],h_[5],h_[6],h_[7]}; \
    L = (f16x8){l_[0],l_[1],l_[2],l_[3],l_[4],l_[5],l_[6],l_[7]}; }
    LOADWBK(0, wbh0, wbl0);
    LOADWBK(1, wbh1, wbl1);
#undef LOADWBK
    // ---- residual: direct batched loads into consuming lanes ----
    float rv[8][4];
    {
        const float* rp = resi + (size_t)b*HWD*64 + 16*wid + lr;
#pragma unroll
        for (int m = 0; m < 8; ++m)
#pragma unroll
        for (int r = 0; r < 4; ++r)
            rv[m][r] = rp[((size_t)(y0+m)*OBJ + x0 + lg*4 + r)*64];
    }
    float g2v = g2[16*wid+lr], b2v = b2[16*wid+lr];
    __syncthreads();               // all waves done with halo before overwrite
    // ---- bn + residual + relu -> thl hi/lo planes (blkout A-frags) ----
    _Float16* thlH = (_Float16*)smem;                 // [128][72] f16
    _Float16* thlL = (_Float16*)(smem + 18432);
#pragma unroll
    for (int m = 0; m < 8; ++m)
#pragma unroll
    for (int r = 0; r < 4; ++r) {
        int pix = m*16 + lg*4 + r;
        float tv = fmaxf(fmaf(acc[m][r], g2v, b2v) + rv[m][r], 0.f);
        _Float16 hi = (_Float16)tv;
        thlH[pix*72 + 16*wid + lr] = hi;
        thlL[pix*72 + 16*wid + lr] = (_Float16)(tv - (float)hi);
    }
    __syncthreads();
    // ---- blkout GEMM (128px x 64ch, K=64) via split-f16 MFMA ----
    f32x4v a2[8];
#pragma unroll
    for (int m=0;m<8;++m) a2[m] = (f32x4v){0.f,0.f,0.f,0.f};
#pragma unroll
    for (int m = 0; m < 8; ++m) {
        int off0 = (m*16 + lr)*72 + lg*8;
        f16x8 ah0 = *(const f16x8*)&thlH[off0];
        f16x8 al0 = *(const f16x8*)&thlL[off0];
        a2[m] = MFMA16(ah0, wbh0, a2[m]);
        a2[m] = MFMA16(al0, wbh0, a2[m]);
        a2[m] = MFMA16(ah0, wbl0, a2[m]);
        f16x8 ah1 = *(const f16x8*)&thlH[off0 + 32];
        f16x8 al1 = *(const f16x8*)&thlL[off0 + 32];
        a2[m] = MFMA16(ah1, wbh1, a2[m]);
        a2[m] = MFMA16(al1, wbh1, a2[m]);
        a2[m] = MFMA16(ah1, wbl1, a2[m]);
    }
    __syncthreads();          // all thl reads done before ureg overwrites
    // ---- write u = blkout + bbk into LDS [128][67] f32 ----
    float* ureg = (float*)smem;
    float bkv = bbk[16*wid+lr];
#pragma unroll
    for (int m = 0; m < 8; ++m)
#pragma unroll
    for (int r = 0; r < 4; ++r) {
        int pix = m*16 + lg*4 + r;
        ureg[pix*67 + 16*wid + lr] = a2[m][r] + bkv;
    }
    __syncthreads();
    // ---- img head (3 outputs, VALU) + sigmoid + normalize ----
    if (t < 128) {
        const float MEAN[3] = {0.485f, 0.456f, 0.406f};
        const float STDV[3] = {0.229f, 0.224f, 0.225f};
        int pix = t, py = pix >> 4, px = pix & 15;
#pragma unroll
        for (int o3 = 0; o3 < 3; ++o3) {
            float s = bim[o3];
            for (int c = 0; c < 64; ++c)
                s = fmaf(wim[o3*64 + c], ureg[pix*67 + c], s);
            float sig = 1.f/(1.f + expf(-s));
            outp[((size_t)(b*3 + o3))*HWD + (size_t)(y0+py)*OBJ + (x0+px)] =
                (sig - MEAN[o3]) / STDV[o3];
        }
    }
}

// ---------------- launch ----------------
extern "C" void kernel_launch(void* const* d_in, const int* in_sizes, int n_in,
                              void* d_out, int out_size, void* d_ws, size_t ws_size,
                              hipStream_t stream) {
    const float* pc      = (const float*)d_in[0];
    const float* w_in    = (const float*)d_in[1];
    const float* b_in    = (const float*)d_in[2];
    const float* w_graph = (const float*)d_in[3];
    const float* gn_g    = (const float*)d_in[4];
    const float* gn_b    = (const float*)d_in[5];
    const float* w_proj  = (const float*)d_in[6];
    const float* b_proj  = (const float*)d_in[7];
    const float* bb_w1   = (const float*)d_in[8];
    const float* bb_g1   = (const float*)d_in[9];
    const float* bb_b1   = (const float*)d_in[10];
    const float* bb_w2   = (const float*)d_in[11];
    const float* bb_g2   = (const float*)d_in[12];
    const float* bb_b2   = (const float*)d_in[13];
    const float* w_blkout= (const float*)d_in[14];
    const float* b_blkout= (const float*)d_in[15];
    const float* w_img   = (const float*)d_in[16];
    const float* b_img   = (const float*)d_in[17];

    float* ws     = (float*)d_ws;
    float* res    = ws + RES_OFF;
    float* h1     = ws + H1_OFF;
    float* pd     = ws + H1_OFF;
    int*   pi     = (int*)(ws + H1_OFF + (size_t)SEG*KNNK*NQ);
    float* f      = ws + F_OFF;
    float* f0     = ws + F0_OFF;
    float* bparam = ws + BP_OFF;
    float* gsum   = ws + GS_OFF;
    float* gmu    = ws + GM_OFF;
    _Float16* wt1f = (_Float16*)(ws + WT1_OFF);
    _Float16* wt2f = (_Float16*)(ws + WT2_OFF);
    int*   lin    = (int*)(ws + INT_OFF);
    int*   nidx   = lin + (size_t)BB*NN*9;
    float* out    = (float*)d_out;

    hipMemsetAsync(res, 0, RES_SZ*sizeof(float), stream);
    hipMemsetAsync(gsum, 0, 64*sizeof(float), stream);

    k0_wtf<<<720, 256, 0, stream>>>(bb_w1, bb_w2, wt1f, wt2f);
    k1_params<<<BB, 256, 0, stream>>>(pc, bparam);
    k23_fused<<<576, 256, 0, stream>>>(pc, bparam, lin, w_in, b_in, f0);
    k4_knn<<<dim3(NN/256, BB, SEG/2), 256, 0, stream>>>(pc, pd, pi, 0);
    k4_knn<<<dim3(NN/256, BB, SEG/2), 256, 0, stream>>>(pc, pd, pi, SEG/2);
    k4b_merge<<<NQ/64, 64, 0, stream>>>(pd, pi, nidx);
    k5_stats<<<(BB*NN)/4, 256, 0, stream>>>(f0, nidx, w_graph, gsum);
    k5b_finalize<<<1, 64, 0, stream>>>(gsum, gmu);
    k6_point<<<(BB*NN)/4, 256, 0, stream>>>(f0, nidx, w_graph, gmu, gn_g, gn_b,
                                            w_proj, b_proj, f);
    k7_scatter<<<(BB*NN)/4, 256, 0, stream>>>(f, lin, res);
    k8m_conv1<<<dim3(14, 28, BB), 256, 0, stream>>>(res, wt1f, bb_g1, bb_b1, h1);
    k9m_conv2<<<dim3(14, 28, BB), 256, 0, stream>>>(h1, wt2f, bb_g2, bb_b2, res,
                                                    w_blkout, b_blkout, w_img, b_img, out);
}

// Round 14
// 549.958 us; speedup vs baseline: 1.2528x; 1.2528x over previous
//
#include <hip/hip_runtime.h>
#include <math.h>

#define BB 8
#define NN 2048
#define KNNK 8
#define SEG 16
#define SEGN (NN/SEG)
#define OBJ 224
#define HWD (OBJ*OBJ)
#define NQ (BB*NN)

// MFMA vector types (gfx950 v_mfma_f32_16x16x32_f16: A/B = 8 x f16, C/D = 4 x f32)
typedef _Float16 f16x8 __attribute__((ext_vector_type(8)));
typedef _Float16 f16x4 __attribute__((ext_vector_type(4)));
typedef float    f32x4v __attribute__((ext_vector_type(4)));

// ---------------- workspace layout (float units) ----------------
constexpr size_t RES_SZ  = (size_t)BB*HWD*64;     // 25,690,112 floats
constexpr size_t F_SZ    = (size_t)BB*NN*64;
constexpr size_t F0_SZ   = (size_t)BB*NN*8;
constexpr size_t RES_OFF = 0;
constexpr size_t H1_OFF  = RES_SZ;                // also aliases KNN partials (pre-conv)
constexpr size_t F_OFF   = 2*RES_SZ;
constexpr size_t F0_OFF  = F_OFF + F_SZ;
constexpr size_t BP_OFF  = F0_OFF + F0_SZ;
constexpr size_t GS_OFF  = BP_OFF + 128;
constexpr size_t GM_OFF  = GS_OFF + 64;
constexpr size_t WT1_OFF = GM_OFF + 64;           // 92160 f16 = 46080 floats (frag weights)
constexpr size_t WTF_SZ  = 46080;
constexpr size_t WT2_OFF = WT1_OFF + WTF_SZ;
constexpr size_t INT_OFF = WT2_OFF + WTF_SZ;

// ---------------- K0: conv weights [O][C][3][3] -> split-f16 MFMA B-frags -
// Layout: wf[(((tap*2 + kb)*2 + hl)*64 + o)*40 + kk], kk = k within 32-block,
// kk-stride padded 32->40 f16. hl=0: hi = (f16)w, hl=1: lo = w - hi.
__global__ void k0_wtf(const float* __restrict__ w, _Float16* __restrict__ wf) {
    int i = blockIdx.x*256 + threadIdx.x;
    if (i >= 92160) return;
    int kk = i % 40;
    int o  = (i/40) & 63;
    int hl = (i/2560) & 1;
    int kb = (i/5120) & 1;
    int tp = i/10240;
    _Float16 v = (_Float16)0.f;
    if (kk < 32) {
        int c = kb*32 + kk;
        float val = w[(size_t)(o*64 + c)*9 + tp];
        _Float16 hi = (_Float16)val;
        v = hl ? (_Float16)(val - (float)hi) : hi;
    }
    wf[i] = v;
}

// ---------------- K1: per-batch grid params — FROZEN (arcp f32, R11) -----
__global__ void k1_params(const float* __restrict__ pc, float* __restrict__ bparam) {
    __shared__ float r0[256], r1[256], r2[256], r3[256];
    __shared__ float sh[4];
    int b = blockIdx.x, t = threadIdx.x;
    const float* p = pc + (size_t)b*NN*3;
    float mnx=1e30f, mxx=-1e30f, mny=1e30f, mxy=-1e30f;
    for (int n=t; n<NN; n+=256) {
        float x=p[3*n], y=p[3*n+1];
        mnx=fminf(mnx,x); mxx=fmaxf(mxx,x); mny=fminf(mny,y); mxy=fmaxf(mxy,y);
    }
    r0[t]=mnx; r1[t]=mxx; r2[t]=mny; r3[t]=mxy;
    __syncthreads();
    for (int s=128; s>0; s>>=1) {
        if (t<s) { r0[t]=fminf(r0[t],r0[t+s]); r1[t]=fmaxf(r1[t],r1[t+s]);
                   r2[t]=fminf(r2[t],r2[t+s]); r3[t]=fmaxf(r3[t],r3[t+s]); }
        __syncthreads();
    }
    if (t==0) {
        float rx = __fsub_rn(r1[0], r0[0]);
        float ry = __fsub_rn(r3[0], r2[0]);
        sh[0]=r0[0]; sh[1]=r2[0];
        float c221 = __fdiv_rn(1.0f, (float)(OBJ-3));
        float grid = __fmul_rn(fmaxf(rx,ry), c221);
        sh[2] = grid;
        sh[3] = __fdiv_rn(1.0f, grid);               // hoisted reciprocal (arcp)
    }
    __syncthreads();
    float minx=sh[0], miny=sh[1], rgrid=sh[3];
    mnx=1e30f; mxx=-1e30f; mny=1e30f; mxy=-1e30f;
    for (int n=t; n<NN; n+=256) {
        float ix = floorf(__fmul_rn(__fsub_rn(p[3*n],   minx), rgrid));
        float iy = floorf(__fmul_rn(__fsub_rn(p[3*n+1], miny), rgrid));
        mnx=fminf(mnx,ix); mxx=fmaxf(mxx,ix); mny=fminf(mny,iy); mxy=fmaxf(mxy,iy);
    }
    __syncthreads();
    r0[t]=mnx; r1[t]=mxx; r2[t]=mny; r3[t]=mxy;
    __syncthreads();
    for (int s=128; s>0; s>>=1) {
        if (t<s) { r0[t]=fminf(r0[t],r0[t+s]); r1[t]=fmaxf(r1[t],r1[t+s]);
                   r2[t]=fminf(r2[t],r2[t+s]); r3[t]=fmaxf(r3[t],r3[t+s]); }
        __syncthreads();
    }
    if (t==0) {
        float cx = floorf((r1[0] + 2.0f + r0[0]) * 0.5f);
        float cy = floorf((r3[0] + 2.0f + r2[0]) * 0.5f);
        bparam[b*8+0]=minx; bparam[b*8+1]=miny; bparam[b*8+2]=sh[3];
        bparam[b*8+3]=112.0f - cx - 1.0f;
        bparam[b*8+4]=112.0f - cy - 1.0f;
    }
}

// ---------------- K2: linear grid indices — FROZEN (arcp) ----------------
__global__ void k2_lin(const float* __restrict__ pc, const float* __restrict__ bparam,
                       int* __restrict__ lin) {
    int i = blockIdx.x*256 + threadIdx.x;
    if (i >= BB*NN) return;
    int b = i / NN;
    float x = pc[(size_t)i*3], y = pc[(size_t)i*3+1];
    float minx=bparam[b*8], miny=bparam[b*8+1], rgrid=bparam[b*8+2];
    float offx=bparam[b*8+3], offy=bparam[b*8+4];
    float ix = floorf(__fmul_rn(__fsub_rn(x, minx), rgrid));
    float iy = floorf(__fmul_rn(__fsub_rn(y, miny), rgrid));
    const float o9x[9] = {-1,-1,-1, 0,0,0, 1,1,1};
    const float o9y[9] = {-1, 0, 1,-1,0,1,-1,0,1};
#pragma unroll
    for (int j=0; j<9; ++j) {
        float dx = ix + o9x[j] + 1.0f + offx;
        float dy = iy + o9y[j] + 1.0f + offy;
        dx += (dx < 0.f ? 1.f : 0.f) - (dx > 223.f ? 1.f : 0.f);
        dy += (dy < 0.f ? 1.f : 0.f) - (dy > 223.f ? 1.f : 0.f);
        lin[(size_t)i*9 + j] = (int)(dx*224.f + dy);
    }
}

// ---------------- K3: f0 = pc @ w_in^T + b_in ----------------
__global__ void k3_f0(const float* __restrict__ pc, const float* __restrict__ w_in,
                      const float* __restrict__ b_in, float* __restrict__ f0) {
    int i = blockIdx.x*256 + threadIdx.x;
    if (i >= BB*NN*8) return;
    int o = i & 7; int bn = i >> 3;
    float x=pc[(size_t)bn*3], y=pc[(size_t)bn*3+1], z=pc[(size_t)bn*3+2];
    f0[i] = x*w_in[o*3] + y*w_in[o*3+1] + z*w_in[o*3+2] + b_in[o];
}

// ---------------- K4: segmented KNN (SEG=16, transposed out) -------------
// VALU-throughput-bound (92% busy) — algorithmic floor for exact scan.
// Partials stored TRANSPOSED pd[(seg*8+j)*NQ + q]: stores here and loads in
// k4b are lane-consecutive in q -> fully-coalesced 256B transactions.
__global__ __launch_bounds__(256) void k4_knn(const float* __restrict__ pc,
                                              float* __restrict__ pd,
                                              int* __restrict__ pi) {
    __shared__ float4 pts[SEGN];
    int b = blockIdx.y, t = threadIdx.x, seg = blockIdx.z;
    const float* p = pc + (size_t)b*NN*3;
    int m0 = seg*SEGN;
    for (int m=t; m<SEGN; m+=256) {
        int mm = m0 + m;
        float x=p[3*mm], y=p[3*mm+1], z=p[3*mm+2];
        float sq = __fadd_rn(__fadd_rn(__fmul_rn(x,x), __fmul_rn(y,y)), __fmul_rn(z,z));
        pts[m] = make_float4(x, y, z, sq);
    }
    __syncthreads();
    int n = blockIdx.x*256 + t;
    float mx = p[3*n], my = p[3*n+1], mz = p[3*n+2];
    float msq = __fadd_rn(__fadd_rn(__fmul_rn(mx,mx), __fmul_rn(my,my)), __fmul_rn(mz,mz));
    float bd[KNNK]; int bi[KNNK];
#pragma unroll
    for (int j=0; j<KNNK; ++j) { bd[j]=1e30f; bi[j]=0; }
#pragma unroll 8
    for (int m=0; m<SEGN; ++m) {
        float4 q = pts[m];
        float dot = __fadd_rn(__fadd_rn(__fmul_rn(mz,q.z), __fmul_rn(my,q.y)),
                              __fmul_rn(mx,q.x));
        float d = __fsub_rn(__fadd_rn(msq, q.w), __fmul_rn(2.0f, dot));
        if (d < bd[KNNK-1]) {
            float v=d; int vi=m0+m;
#pragma unroll
            for (int j=0; j<KNNK; ++j) {
                if (v < bd[j]) { float tv=bd[j]; int ti=bi[j]; bd[j]=v; bi[j]=vi; v=tv; vi=ti; }
            }
        }
    }
    size_t qidx = (size_t)b*NN + n;
#pragma unroll
    for (int j=0; j<KNNK; ++j) {
        pd[(size_t)(seg*KNNK + j)*NQ + qidx] = bd[j];
        pi[(size_t)(seg*KNNK + j)*NQ + qidx] = bi[j];
    }
}

// ---------------- K4b: 4-thread cooperative merge (R14) ------------------
// R13 PMC: old k4b = 130us, VALUBusy 2.1%, Occupancy 2.9% (1 wave/CU, 128
// serially-exposed L2 latencies). Now: tid = ql + 64*tt; thread tt inserts
// segments [4tt,4tt+4) (32 coalesced pairs); partial top-8s -> padded LDS;
// tt==0 inserts the 4 sorted lists in tt-major/j-minor order.
// EXACTNESS: phase-1 drops only elements dominated by >=8 in-group (cannot
// be global top-8); both phases present equal-d elements in ascending index
// (groups = ascending contiguous ranges, lists lex-sorted); strict-less
// keeps first-seen -> identical lex top-8 + ties to the R12-verified kernel.
// Grid 256 blocks x 256 thr = all CUs, 4 waves/CU.
__global__ __launch_bounds__(256) void k4b_merge(const float* __restrict__ pd,
                                                 const int* __restrict__ pi,
                                                 int* __restrict__ nidx) {
    __shared__ float sd[4][64][9];     // [tt][ql][j], pad 8->9: conflict-free
    __shared__ int   si[4][64][9];
    int t = threadIdx.x;
    int ql = t & 63, tt = t >> 6;
    int q = blockIdx.x*64 + ql;
    float bd[KNNK]; int bi[KNNK];
#pragma unroll
    for (int j=0; j<KNNK; ++j) { bd[j]=1e30f; bi[j]=0x7fffffff; }
    // ---- phase 1: segments [4tt, 4tt+4), s-major j-minor, strict-less ----
#pragma unroll
    for (int ss=0; ss<4; ++ss) {
        int s = tt*4 + ss;
#pragma unroll
        for (int j=0; j<KNNK; ++j) {
            float v = pd[(size_t)(s*KNNK + j)*NQ + q];
            int  vi = pi[(size_t)(s*KNNK + j)*NQ + q];
            if (v < bd[KNNK-1]) {
                float cv=v; int ci=vi;
#pragma unroll
                for (int k=0; k<KNNK; ++k) {
                    if (cv < bd[k]) { float tv=bd[k]; int ti=bi[k]; bd[k]=cv; bi[k]=ci; cv=tv; ci=ti; }
                }
            }
        }
    }
#pragma unroll
    for (int j=0; j<KNNK; ++j) { sd[tt][ql][j] = bd[j]; si[tt][ql][j] = bi[j]; }
    __syncthreads();
    // ---- phase 2: tt==0 merges 4 sorted lists (tt-major, j-minor) ----
    if (tt == 0) {
        float md[KNNK]; int mi[KNNK];
#pragma unroll
        for (int j=0; j<KNNK; ++j) { md[j]=1e30f; mi[j]=0x7fffffff; }
#pragma unroll
        for (int t2=0; t2<4; ++t2) {
#pragma unroll
            for (int j=0; j<KNNK; ++j) {
                float v = sd[t2][ql][j];
                int  vi = si[t2][ql][j];
                if (v < md[KNNK-1]) {
                    float cv=v; int ci=vi;
#pragma unroll
                    for (int k=0; k<KNNK; ++k) {
                        if (cv < md[k]) { float tv=md[k]; int ti=mi[k]; md[k]=cv; mi[k]=ci; cv=tv; ci=ti; }
                    }
                }
            }
        }
#pragma unroll
        for (int j=0; j<KNNK; ++j) nidx[(size_t)q*KNNK + j] = mi[j];
    }
}

// ---------------- feat builder (shared by K5/K6) ----------------
__device__ __forceinline__ void build_feat(int t, int b, int n0,
        const float* __restrict__ f0, const int* __restrict__ nidx,
        float feat[4][8][16]) {
    int pt = t >> 6, k = (t >> 3) & 7, c = t & 7;
    int n  = n0 + pt;
    int nb = nidx[((size_t)b*NN + n)*8 + k];
    float f0c = f0[((size_t)b*NN + n)*8 + c];
    float fnc = f0[((size_t)b*NN + nb)*8 + c];
    feat[pt][k][c]   = fnc - f0c;
    feat[pt][k][c+8] = f0c;
}

// ---------------- K5: GroupNorm stats pass ----------------
__global__ __launch_bounds__(256) void k5_stats(const float* __restrict__ f0,
        const int* __restrict__ nidx, const float* __restrict__ w_graph,
        float* __restrict__ gsum) {
    __shared__ float wgT[16*64];
    __shared__ float feat[4][8][16];
    __shared__ float part[4][4][2];
    int t = threadIdx.x;
    for (int i=t; i<1024; i+=256) wgT[(i&15)*64 + (i>>4)] = w_graph[i];
    int blk = blockIdx.x;
    int b = blk >> 9, n0 = (blk & 511)*4;
    build_feat(t, b, n0, f0, nidx, feat);
    __syncthreads();
    int pt = t >> 6, o = t & 63;
    float s = 0.f, s2 = 0.f;
#pragma unroll
    for (int k=0; k<8; ++k) {
        float g = 0.f;
#pragma unroll
        for (int c=0; c<16; ++c) g = fmaf(feat[pt][k][c], wgT[c*64+o], g);
        s += g; s2 += g*g;
    }
#pragma unroll
    for (int off=8; off; off>>=1) {
        s  += __shfl_down(s,  off, 16);
        s2 += __shfl_down(s2, off, 16);
    }
    if ((o & 15) == 0) { part[pt][o>>4][0] = s; part[pt][o>>4][1] = s2; }
    __syncthreads();
    if (t < 8) {
        int grp = t >> 1, which = t & 1;
        float v = part[0][grp][which] + part[1][grp][which]
                + part[2][grp][which] + part[3][grp][which];
        atomicAdd(&gsum[(b*4+grp)*2 + which], v);
    }
}

__global__ void k5b_finalize(const float* __restrict__ gsum, float* __restrict__ gmu) {
    int t = threadIdx.x;
    if (t < 32) {
        const float cnt = (float)(NN*KNNK*16);
        float mu = gsum[t*2] / cnt;
        float var = gsum[t*2+1] / cnt - mu*mu;
        gmu[t*2]   = mu;
        gmu[t*2+1] = 1.0f / sqrtf(var + 1e-5f);
    }
}

// ---------------- K6: normalize + leaky + max_k + proj ----------------
__global__ __launch_bounds__(256) void k6_point(const float* __restrict__ f0,
        const int* __restrict__ nidx, const float* __restrict__ w_graph,
        const float* __restrict__ gmu, const float* __restrict__ gn_g,
        const float* __restrict__ gn_b, const float* __restrict__ w_proj,
        const float* __restrict__ b_proj, float* __restrict__ f) {
    __shared__ float wgT[16*64];
    __shared__ float wpT[64*64];
    __shared__ float feat[4][8][16];
    __shared__ float gmax_s[4][64];
    int t = threadIdx.x;
    for (int i=t; i<1024; i+=256) wgT[(i&15)*64 + (i>>4)] = w_graph[i];
    for (int i=t; i<4096; i+=256) wpT[(i&63)*64 + (i>>6)] = w_proj[i];
    int blk = blockIdx.x;
    int b = blk >> 9, n0 = (blk & 511)*4;
    build_feat(t, b, n0, f0, nidx, feat);
    __syncthreads();
    int pt = t >> 6, o = t & 63;
    int grp = o >> 4;
    float mu = gmu[(b*4+grp)*2], rsig = gmu[(b*4+grp)*2+1];
    float ga = gn_g[o], be = gn_b[o];
    float gm = -1e30f;
#pragma unroll
    for (int k=0; k<8; ++k) {
        float g = 0.f;
#pragma unroll
        for (int c=0; c<16; ++c) g = fmaf(feat[pt][k][c], wgT[c*64+o], g);
        float v = (g - mu)*rsig*ga + be;
        v = (v >= 0.f) ? v : 0.2f*v;
        gm = fmaxf(gm, v);
    }
    gmax_s[pt][o] = gm;
    __syncthreads();
    float acc = b_proj[o];
#pragma unroll
    for (int c=0; c<64; ++c) acc = fmaf(gmax_s[pt][c], wpT[c*64+o], acc);
    f[((size_t)b*NN + n0 + pt)*64 + o] = acc;
}

// ---------------- K7: scatter-sum onto NHWC grid (all batches) -----------
__global__ __launch_bounds__(256) void k7_scatter(const float* __restrict__ f,
        const int* __restrict__ lin, float* __restrict__ res) {
    int blk = blockIdx.x, t = threadIdx.x;
    int b = blk >> 9;
    int n = (blk & 511)*4 + (t >> 6);
    int o = t & 63;
    size_t bn = (size_t)b*NN + n;
    float v = f[bn*64 + o];
#pragma unroll
    for (int j=0; j<9; ++j) {
        int cell = lin[bn*9 + j];
        if (cell >= 0 && cell < HWD)
            atomicAdd(&res[((size_t)b*HWD + cell)*64 + o], v);
    }
}

// ======================= split-f16 MFMA conv engine (R10 config, frozen) ==
// R10: row-major K-loop (ds_read 288->120/wave) + all-36-frag weights in
// registers at (256,1). R13 PMC: k9m 124us MfmaUtil 32%. FROZEN.
#define LDS4_BYTES 51840   // haloH [180][72]f16 + haloL

#define MFMA16(A,B,C) __builtin_amdgcn_mfma_f32_16x16x32_f16(A,B,C,0,0,0)

// one halo row R: load 12 A-frags, apply all valid (dy,dx) taps.
// m = R - dy must be in [0,7]; bounds are compile-time for literal R.
#define ROWC(R) { \
    f16x8 ah0[3], al0[3], ah1[3], al1[3]; \
    _Pragma("unroll") \
    for (int dx = 0; dx < 3; ++dx) { \
        int off_ = ((R)*18 + lr + dx)*72 + lg*8; \
        ah0[dx] = *(const f16x8*)&haloH[off_]; \
        al0[dx] = *(const f16x8*)&haloL[off_]; \
        ah1[dx] = *(const f16x8*)&haloH[off_ + 32]; \
        al1[dx] = *(const f16x8*)&haloL[off_ + 32]; \
    } \
    _Pragma("unroll") \
    for (int dy = 0; dy < 3; ++dy) { \
        if ((R) - dy >= 0 && (R) - dy <= 7) { \
            _Pragma("unroll") \
            for (int dx = 0; dx < 3; ++dx) { \
                acc[(R)-dy] = MFMA16(ah0[dx], wh0[dy*3+dx], acc[(R)-dy]); \
                acc[(R)-dy] = MFMA16(al0[dx], wh0[dy*3+dx], acc[(R)-dy]); \
                acc[(R)-dy] = MFMA16(ah0[dx], wl0[dy*3+dx], acc[(R)-dy]); \
                acc[(R)-dy] = MFMA16(ah1[dx], wh1[dy*3+dx], acc[(R)-dy]); \
                acc[(R)-dy] = MFMA16(al1[dx], wh1[dy*3+dx], acc[(R)-dy]); \
                acc[(R)-dy] = MFMA16(ah1[dx], wl1[dy*3+dx], acc[(R)-dy]); \
            } \
        } \
    } }

__device__ __forceinline__ void conv_mfma_body(
        const float* __restrict__ sp, const _Float16* __restrict__ wf,
        _Float16* haloH, _Float16* haloL,
        int x0, int y0, int t, int wid, int lr, int lg, f32x4v acc[8]) {
    // ---- halo stage: 10x18 cells x 64ch fp32 -> hi/lo f16 (batched) ----
    float4 vreg[12];
#pragma unroll
    for (int j = 0; j < 12; ++j) {
        int i = j*256 + t; if (i > 2879) i = 2879;     // dup-load, harmless
        int cell = i >> 4, c4 = i & 15;
        int gy = y0 - 1 + cell/18, gx = x0 - 1 + cell%18;
        int cy = gy < 0 ? 0 : (gy > OBJ-1 ? OBJ-1 : gy);
        int cx = gx < 0 ? 0 : (gx > OBJ-1 ? OBJ-1 : gx);
        vreg[j] = *(const float4*)(sp + ((size_t)cy*OBJ + cx)*64 + c4*4);
    }
#pragma unroll
    for (int j = 0; j < 12; ++j) {
        int i = j*256 + t;
        if (i <= 2879) {
            int cell = i >> 4, c4 = i & 15;
            int gy = y0 - 1 + cell/18, gx = x0 - 1 + cell%18;
            bool inb = ((unsigned)gy < (unsigned)OBJ) && ((unsigned)gx < (unsigned)OBJ);
            float4 v = vreg[j];
            if (!inb) v = make_float4(0.f,0.f,0.f,0.f);
            _Float16 a0=(_Float16)v.x, a1=(_Float16)v.y, a2=(_Float16)v.z, a3=(_Float16)v.w;
            f16x4 hv = {a0, a1, a2, a3};
            f16x4 lv = {(_Float16)(v.x-(float)a0), (_Float16)(v.y-(float)a1),
                        (_Float16)(v.z-(float)a2), (_Float16)(v.w-(float)a3)};
            *(f16x4*)&haloH[cell*72 + c4*4] = hv;
            *(f16x4*)&haloL[cell*72 + c4*4] = lv;
        }
    }
    // ---- all 36 weight B-frags into registers (144 VGPR, L2-hot) ----
    // wf addr = tap*10240 + kb*5120 + hl*2560 + o*40 + kk
    const int obase = (16*wid + lr)*40 + lg*8;
    f16x8 wh0[9], wl0[9], wh1[9], wl1[9];
#pragma unroll
    for (int tp = 0; tp < 9; ++tp) {
        const _Float16* wb_ = wf + (size_t)(tp*10240) + obase;
        wh0[tp] = *(const f16x8*)wb_;
        wl0[tp] = *(const f16x8*)(wb_ + 2560);
        wh1[tp] = *(const f16x8*)(wb_ + 5120);
        wl1[tp] = *(const f16x8*)(wb_ + 7680);
    }
    __syncthreads();
    // ---- barrier-free row-major K-loop: 10 halo rows ----
    ROWC(0) ROWC(1) ROWC(2) ROWC(3) ROWC(4)
    ROWC(5) ROWC(6) ROWC(7) ROWC(8) ROWC(9)
}

// ---------------- K8: conv3x3 + scale/shift + relu (MFMA, 16x8 tile) -----
__global__ __launch_bounds__(256, 1) void k8m_conv1(
        const float* __restrict__ src, const _Float16* __restrict__ wf,
        const float* __restrict__ g1, const float* __restrict__ b1,
        float* __restrict__ dst) {
    __shared__ __align__(16) char smem[LDS4_BYTES];
    _Float16* haloH = (_Float16*)smem;
    _Float16* haloL = (_Float16*)(smem + 25920);
    // XCD swizzle: batch = flat&7, tile = flat>>3 (bijective, 3136%8==0)
    int flat = blockIdx.x + 14*(blockIdx.y + 28*blockIdx.z);
    int b = flat & 7, rem = flat >> 3;
    int by = rem/14, bx = rem - by*14;
    int x0 = bx*16, y0 = by*8;
    int t = threadIdx.x, wid = t >> 6, lr = t & 15, lg = (t >> 4) & 3;
    f32x4v acc[8];
#pragma unroll
    for (int m=0;m<8;++m) acc[m] = (f32x4v){0.f,0.f,0.f,0.f};
    conv_mfma_body(src + (size_t)b*HWD*64, wf, haloH, haloL,
                   x0, y0, t, wid, lr, lg, acc);
    // ---- epilogue: scale/shift + relu, store NHWC ----
    float gv = g1[16*wid+lr], bv = b1[16*wid+lr];
    float* dp = dst + (size_t)b*HWD*64;
#pragma unroll
    for (int m = 0; m < 8; ++m) {
        size_t rowb = ((size_t)(y0+m)*OBJ + x0)*64 + 16*wid + lr;
#pragma unroll
        for (int r = 0; r < 4; ++r) {
            int px = lg*4 + r;
            dp[rowb + (size_t)px*64] = fmaxf(fmaf(acc[m][r], gv, bv), 0.f);
        }
    }
}

// ---------------- K9: conv3x3 + bn + residual-relu + blkout + img head ---
__global__ __launch_bounds__(256, 1) void k9m_conv2(
        const float* __restrict__ h1, const _Float16* __restrict__ wf,
        const float* __restrict__ g2, const float* __restrict__ b2,
        const float* __restrict__ resi,
        const float* __restrict__ wbk, const float* __restrict__ bbk,
        const float* __restrict__ wim, const float* __restrict__ bim,
        float* __restrict__ outp) {
    __shared__ __align__(16) char smem[LDS4_BYTES];
    _Float16* haloH = (_Float16*)smem;
    _Float16* haloL = (_Float16*)(smem + 25920);
    int flat = blockIdx.x + 14*(blockIdx.y + 28*blockIdx.z);
    int b = flat & 7, rem = flat >> 3;
    int by = rem/14, bx = rem - by*14;
    int x0 = bx*16, y0 = by*8;
    int t = threadIdx.x, wid = t >> 6, lr = t & 15, lg = (t >> 4) & 3;
    f32x4v acc[8];
#pragma unroll
    for (int m=0;m<8;++m) acc[m] = (f32x4v){0.f,0.f,0.f,0.f};
    conv_mfma_body(h1 + (size_t)b*HWD*64, wf, haloH, haloL,
                   x0, y0, t, wid, lr, lg, acc);
    // ---- wbk B-frags: global f32 -> hi/lo f16 regs (named, no staging) ----
    f16x8 wbh0, wbl0, wbh1, wbl1;
#define LOADWBK(KB, H, L) { \
    const float* wp_ = wbk + (size_t)(16*wid+lr)*64 + (KB)*32 + lg*8; \
    float4 w0_ = *(const float4*)wp_; \
    float4 w1_ = *(const float4*)(wp_+4); \
    const float* we_ = (const float*)&w0_; \
    const float* wo_ = (const float*)&w1_; \
    _Float16 h_[8]; _Float16 l_[8]; \
    _Pragma("unroll") \
    for (int e=0;e<4;++e) { h_[e]=(_Float16)we_[e]; l_[e]=(_Float16)(we_[e]-(float)h_[e]); } \
    _Pragma("unroll") \
    for (int e=0;e<4;++e) { h_[4+e]=(_Float16)wo_[e]; l_[4+e]=(_Float16)(wo_[e]-(float)h_[4+e]); } \
    H = (f16x8){h_[0],h_[1],h_[2],h_[3],h_[4],h_[5],h_[6],h_[7]}; \
    L = (f16x8){l_[0],l_[1],l_[2],l_[3],l_[4],l_[5],l_[6],l_[7]}; }
    LOADWBK(0, wbh0, wbl0);
    LOADWBK(1, wbh1, wbl1);
#undef LOADWBK
    // ---- residual: direct batched loads into consuming lanes ----
    float rv[8][4];
    {
        const float* rp = resi + (size_t)b*HWD*64 + 16*wid + lr;
#pragma unroll
        for (int m = 0; m < 8; ++m)
#pragma unroll
        for (int r = 0; r < 4; ++r)
            rv[m][r] = rp[((size_t)(y0+m)*OBJ + x0 + lg*4 + r)*64];
    }
    float g2v = g2[16*wid+lr], b2v = b2[16*wid+lr];
    __syncthreads();               // all waves done with halo before overwrite
    // ---- bn + residual + relu -> thl hi/lo planes (blkout A-frags) ----
    _Float16* thlH = (_Float16*)smem;                 // [128][72] f16
    _Float16* thlL = (_Float16*)(smem + 18432);
#pragma unroll
    for (int m = 0; m < 8; ++m)
#pragma unroll
    for (int r = 0; r < 4; ++r) {
        int pix = m*16 + lg*4 + r;
        float tv = fmaxf(fmaf(acc[m][r], g2v, b2v) + rv[m][r], 0.f);
        _Float16 hi = (_Float16)tv;
        thlH[pix*72 + 16*wid + lr] = hi;
        thlL[pix*72 + 16*wid + lr] = (_Float16)(tv - (float)hi);
    }
    __syncthreads();
    // ---- blkout GEMM (128px x 64ch, K=64) via split-f16 MFMA ----
    f32x4v a2[8];
#pragma unroll
    for (int m=0;m<8;++m) a2[m] = (f32x4v){0.f,0.f,0.f,0.f};
#pragma unroll
    for (int m = 0; m < 8; ++m) {
        int off0 = (m*16 + lr)*72 + lg*8;
        f16x8 ah0 = *(const f16x8*)&thlH[off0];
        f16x8 al0 = *(const f16x8*)&thlL[off0];
        a2[m] = MFMA16(ah0, wbh0, a2[m]);
        a2[m] = MFMA16(al0, wbh0, a2[m]);
        a2[m] = MFMA16(ah0, wbl0, a2[m]);
        f16x8 ah1 = *(const f16x8*)&thlH[off0 + 32];
        f16x8 al1 = *(const f16x8*)&thlL[off0 + 32];
        a2[m] = MFMA16(ah1, wbh1, a2[m]);
        a2[m] = MFMA16(al1, wbh1, a2[m]);
        a2[m] = MFMA16(ah1, wbl1, a2[m]);
    }
    __syncthreads();          // all thl reads done before ureg overwrites
    // ---- write u = blkout + bbk into LDS [128][67] f32 ----
    float* ureg = (float*)smem;
    float bkv = bbk[16*wid+lr];
#pragma unroll
    for (int m = 0; m < 8; ++m)
#pragma unroll
    for (int r = 0; r < 4; ++r) {
        int pix = m*16 + lg*4 + r;
        ureg[pix*67 + 16*wid + lr] = a2[m][r] + bkv;
    }
    __syncthreads();
    // ---- img head (3 outputs, VALU) + sigmoid + normalize ----
    if (t < 128) {
        const float MEAN[3] = {0.485f, 0.456f, 0.406f};
        const float STDV[3] = {0.229f, 0.224f, 0.225f};
        int pix = t, py = pix >> 4, px = pix & 15;
#pragma unroll
        for (int o3 = 0; o3 < 3; ++o3) {
            float s = bim[o3];
            for (int c = 0; c < 64; ++c)
                s = fmaf(wim[o3*64 + c], ureg[pix*67 + c], s);
            float sig = 1.f/(1.f + expf(-s));
            outp[((size_t)(b*3 + o3))*HWD + (size_t)(y0+py)*OBJ + (x0+px)] =
                (sig - MEAN[o3]) / STDV[o3];
        }
    }
}

// ---------------- launch ----------------
extern "C" void kernel_launch(void* const* d_in, const int* in_sizes, int n_in,
                              void* d_out, int out_size, void* d_ws, size_t ws_size,
                              hipStream_t stream) {
    const float* pc      = (const float*)d_in[0];
    const float* w_in    = (const float*)d_in[1];
    const float* b_in    = (const float*)d_in[2];
    const float* w_graph = (const float*)d_in[3];
    const float* gn_g    = (const float*)d_in[4];
    const float* gn_b    = (const float*)d_in[5];
    const float* w_proj  = (const float*)d_in[6];
    const float* b_proj  = (const float*)d_in[7];
    const float* bb_w1   = (const float*)d_in[8];
    const float* bb_g1   = (const float*)d_in[9];
    const float* bb_b1   = (const float*)d_in[10];
    const float* bb_w2   = (const float*)d_in[11];
    const float* bb_g2   = (const float*)d_in[12];
    const float* bb_b2   = (const float*)d_in[13];
    const float* w_blkout= (const float*)d_in[14];
    const float* b_blkout= (const float*)d_in[15];
    const float* w_img   = (const float*)d_in[16];
    const float* b_img   = (const float*)d_in[17];

    float* ws     = (float*)d_ws;
    float* res    = ws + RES_OFF;
    float* h1     = ws + H1_OFF;
    float* pd     = ws + H1_OFF;
    int*   pi     = (int*)(ws + H1_OFF + (size_t)SEG*KNNK*NQ);
    float* f      = ws + F_OFF;
    float* f0     = ws + F0_OFF;
    float* bparam = ws + BP_OFF;
    float* gsum   = ws + GS_OFF;
    float* gmu    = ws + GM_OFF;
    _Float16* wt1f = (_Float16*)(ws + WT1_OFF);
    _Float16* wt2f = (_Float16*)(ws + WT2_OFF);
    int*   lin    = (int*)(ws + INT_OFF);
    int*   nidx   = lin + (size_t)BB*NN*9;
    float* out    = (float*)d_out;

    hipMemsetAsync(res, 0, RES_SZ*sizeof(float), stream);
    hipMemsetAsync(gsum, 0, 64*sizeof(float), stream);

    k0_wtf<<<360, 256, 0, stream>>>(bb_w1, wt1f);
    k0_wtf<<<360, 256, 0, stream>>>(bb_w2, wt2f);
    k1_params<<<BB, 256, 0, stream>>>(pc, bparam);
    k2_lin<<<(BB*NN)/256, 256, 0, stream>>>(pc, bparam, lin);
    k3_f0<<<(BB*NN*8)/256, 256, 0, stream>>>(pc, w_in, b_in, f0);
    k4_knn<<<dim3(NN/256, BB, SEG), 256, 0, stream>>>(pc, pd, pi);
    k4b_merge<<<NQ/64, 256, 0, stream>>>(pd, pi, nidx);
    k5_stats<<<(BB*NN)/4, 256, 0, stream>>>(f0, nidx, w_graph, gsum);
    k5b_finalize<<<1, 64, 0, stream>>>(gsum, gmu);
    k6_point<<<(BB*NN)/4, 256, 0, stream>>>(f0, nidx, w_graph, gmu, gn_g, gn_b,
                                            w_proj, b_proj, f);
    k7_scatter<<<(BB*NN)/4, 256, 0, stream>>>(f, lin, res);
    k8m_conv1<<<dim3(14, 28, BB), 256, 0, stream>>>(res, wt1f, bb_g1, bb_b1, h1);
    k9m_conv2<<<dim3(14, 28, BB), 256, 0, stream>>>(h1, wt2f, bb_g2, bb_b2, res,
                                                    w_blkout, b_blkout, w_img, b_img, out);
}